// Round 4
// baseline (3720.327 us; speedup 1.0000x reference)
//
#include <hip/hip_runtime.h>

namespace {

typedef _Float16 h2 __attribute__((ext_vector_type(2)));

constexpr int KSTEPS = 512;
constexpr int NSTATE = 128;
constexpr int NINPUT = 32;
constexpr int HID    = 256;
constexpr int FANIN  = 161;

// per-trajectory z (f16): [y 0..127 | u 128..159 | t 160 | zero pad 161..191]
constexpr int ZST = 192;
// per-trajectory h: 8 chunks, stride 40 f16 (32 valid + 8 pad), conflict-free
constexpr int HCH = 40;
constexpr int HST = 8 * HCH;   // 320

__device__ __forceinline__ float fdot2(h2 a, h2 b, float c) {
#if __has_builtin(__builtin_amdgcn_fdot2)
  return __builtin_amdgcn_fdot2(a, b, c, false);
#else
  return c + (float)a[0] * (float)b[0] + (float)a[1] * (float)b[1];
#endif
}

__device__ __forceinline__ float fast_tanh(float x) {
  float e2 = __expf(2.0f * x);
  return 1.0f - 2.0f / (e2 + 1.0f);
}

template <int CTRL>
__device__ __forceinline__ float dpp_add(float x) {
  int y = __builtin_amdgcn_update_dpp(0, __float_as_int(x), CTRL, 0xF, 0xF, false);
  return x + __int_as_float(y);
}
// sum across 8 consecutive lanes
__device__ __forceinline__ float red8(float x) {
  x = dpp_add<0xB1>(x);    // xor 1
  x = dpp_add<0x4E>(x);    // xor 2
  x = dpp_add<0x141>(x);   // half-row mirror (xor 4..7 equiv after quads)
  return x;
}

// Barrier with LDS-only drain: skips the vmcnt(0) drain __syncthreads() forces,
// so global out-stores / us-loads stay in flight across stage boundaries.
#define BAR() __asm__ volatile("s_waitcnt lgkmcnt(0)\n\ts_barrier" ::: "memory")

union F4 { float4 f; h2 h[4]; };

// 32 blocks x 512 threads; each block = 2 independent trajectories x 256 thr.
// Per trajectory (lt = 0..255): g = lt>>3 (0..31), kc = lt&7.
//  Layer1: rows 8g..8g+7 x z-chunk kc (24 f16). Layer2: rows 4g..4g+3 x h-chunk kc (32 f16).
//  Reductions: 3-step DPP butterfly over the 8 kc lanes.
__global__ __launch_bounds__(512, 2)
void ode_tsit5_kernel(const float* __restrict__ ts,
                      const float* __restrict__ y0,
                      const float* __restrict__ us,
                      const float* __restrict__ W1,
                      const float* __restrict__ b1,
                      const float* __restrict__ W2,
                      const float* __restrict__ b2,
                      float* __restrict__ out)
{
  const int traj = threadIdx.x >> 8;   // 0/1
  const int lt   = threadIdx.x & 255;
  const int g    = lt >> 3;            // 0..31
  const int kc   = lt & 7;             // 0..7
  const int b    = blockIdx.x * 2 + traj;

  __shared__ __align__(16) _Float16 z16[2][ZST];
  __shared__ __align__(16) _Float16 hs[2][HST];

  // ---- pack weights into f16-pair registers ----
  // z position p -> W1 column: p<160 -> p+1 (y,u), p==160 -> 0 (t), else 0 (pad).
  h2 w1[8][12];
  #pragma unroll
  for (int r = 0; r < 8; ++r) {
    const float* row = W1 + (long)(8 * g + r) * FANIN;
    #pragma unroll
    for (int i = 0; i < 12; ++i) {
      const int p0 = 24 * kc + 2 * i;
      const int p1 = p0 + 1;
      const float f0 = (p0 < 160) ? row[p0 + 1] : ((p0 == 160) ? row[0] : 0.0f);
      const float f1 = (p1 < 160) ? row[p1 + 1] : ((p1 == 160) ? row[0] : 0.0f);
      w1[r][i] = h2{(_Float16)f0, (_Float16)f1};
    }
  }
  h2 w2[4][16];
  #pragma unroll
  for (int r = 0; r < 4; ++r) {
    const float* row = W2 + (long)(4 * g + r) * HID + 32 * kc;
    #pragma unroll
    for (int i = 0; i < 16; ++i)
      w2[r][i] = h2{(_Float16)row[2 * i], (_Float16)row[2 * i + 1]};
  }

  const int   jrow = 8 * g + kc;                      // this lane's layer1 store row
  const float b1r  = b1[jrow];
  const int   hidx = HCH * (jrow >> 5) + (jrow & 31);
  const int   orow = 4 * g + kc;                      // layer2 row (kc<4)
  const float b2r  = (kc < 4) ? b2[orow] : 0.0f;

  // Tsit5 tableau (b7 = 0 path)
  constexpr float Cc[5] = {0.161f, 0.327f, 0.9f, 0.9800255409045097f, 1.0f};
  constexpr double CcD[5] = {0.161, 0.327, 0.9, 0.9800255409045097, 1.0};
  constexpr float Af[5][5] = {
    {0.161f, 0.f, 0.f, 0.f, 0.f},
    {-0.008480655492356989f, 0.335480655492357f, 0.f, 0.f, 0.f},
    {2.8971530571054935f, -6.359448489975075f, 4.3622954328695815f, 0.f, 0.f},
    {5.325864828439257f, -11.748883564062828f, 7.4955393428898365f, -0.09249506636175525f, 0.f},
    {5.86145544294642f, -12.92096931784711f, 8.159367898576159f, -0.071584973281401f,
     -0.028269050394068383f}};
  constexpr float Bf[6] = {0.09646076681806523f, 0.01f, 0.4798896504144996f,
                           1.379008574103742f, -3.290069515436081f, 2.324710524099774f};

  // ---- init ----
  float yR = 0.0f, ksR[6] = {0.f, 0.f, 0.f, 0.f, 0.f, 0.f};
  if (kc < 4) {
    yR = y0[(long)b * NSTATE + orow];
    z16[traj][orow] = (_Float16)yR;
    out[(long)b * KSTEPS * NSTATE + orow] = yR;
  }
  if (lt < ZST - FANIN) z16[traj][FANIN + lt] = (_Float16)0.0f;  // pad, never rewritten

  const bool is_u = (kc == 4);
  const int  m    = g;                    // u component for kc==4 lanes
  const float* usb = us + (long)b * KSTEPS * NINPUT;
  float u0v = 0.f, u1v = 0.f, u2v = 0.f, uprev = 0.f;
  if (is_u) {
    u0v = usb[m];
    u1v = usb[NINPUT + m];
    z16[traj][128 + m] = (_Float16)u0v;
  }
  float tcur = ts[0], tn1 = ts[1];
  float dtp  = 1.0f;
  if (lt == 5) z16[traj][160] = (_Float16)tcur;

  for (int i = 0; i < KSTEPS - 1; ++i) {
    const float dt = tn1 - tcur;
    const int   i2 = (i + 2 < KSTEPS) ? (i + 2) : (KSTEPS - 1);
    const float tn2 = ts[i2];                       // prefetch, used next step
    if (is_u) u2v = usb[(long)i2 * NINPUT + m];     // prefetch, used next step

    float hd0v = 0.f;
    if (is_u) hd0v = (i == 0) ? (u1v - u0v) : (u0v - uprev) * (dt / dtp);

    #pragma unroll
    for (int e = 0; e < 6; ++e) {
      BAR();   // z16 ready (LDS-only drain)

      // ---- layer 1: 8 rows x 24-f16 z chunk ----
      const F4* zp = (const F4*)(&z16[traj][24 * kc]);
      F4 zc0 = zp[0], zc1 = zp[1], zc2 = zp[2];
      float acc[8];
      #pragma unroll
      for (int r = 0; r < 8; ++r) {
        float a = fdot2(w1[r][0], zc0.h[0], 0.0f);
        a = fdot2(w1[r][1],  zc0.h[1], a);
        a = fdot2(w1[r][2],  zc0.h[2], a);
        a = fdot2(w1[r][3],  zc0.h[3], a);
        a = fdot2(w1[r][4],  zc1.h[0], a);
        a = fdot2(w1[r][5],  zc1.h[1], a);
        a = fdot2(w1[r][6],  zc1.h[2], a);
        a = fdot2(w1[r][7],  zc1.h[3], a);
        a = fdot2(w1[r][8],  zc2.h[0], a);
        a = fdot2(w1[r][9],  zc2.h[1], a);
        a = fdot2(w1[r][10], zc2.h[2], a);
        a = fdot2(w1[r][11], zc2.h[3], a);
        acc[r] = a;
      }
      #pragma unroll
      for (int r = 0; r < 8; ++r) acc[r] = red8(acc[r]);
      // lane kc stores row 8g+kc
      float sel = acc[0];
      #pragma unroll
      for (int r = 1; r < 8; ++r) sel = (kc == r) ? acc[r] : sel;
      hs[traj][hidx] = (_Float16)fast_tanh(b1r + sel);

      BAR();   // hs ready

      // ---- layer 2: 4 rows x 32-f16 h chunk ----
      const F4* hp4 = (const F4*)(&hs[traj][HCH * kc]);
      F4 hc0 = hp4[0], hc1 = hp4[1], hc2 = hp4[2], hc3 = hp4[3];
      float a2[4];
      #pragma unroll
      for (int r = 0; r < 4; ++r) {
        float c = fdot2(w2[r][0], hc0.h[0], 0.0f);
        c = fdot2(w2[r][1],  hc0.h[1], c);
        c = fdot2(w2[r][2],  hc0.h[2], c);
        c = fdot2(w2[r][3],  hc0.h[3], c);
        c = fdot2(w2[r][4],  hc1.h[0], c);
        c = fdot2(w2[r][5],  hc1.h[1], c);
        c = fdot2(w2[r][6],  hc1.h[2], c);
        c = fdot2(w2[r][7],  hc1.h[3], c);
        c = fdot2(w2[r][8],  hc2.h[0], c);
        c = fdot2(w2[r][9],  hc2.h[1], c);
        c = fdot2(w2[r][10], hc2.h[2], c);
        c = fdot2(w2[r][11], hc2.h[3], c);
        c = fdot2(w2[r][12], hc3.h[0], c);
        c = fdot2(w2[r][13], hc3.h[1], c);
        c = fdot2(w2[r][14], hc3.h[2], c);
        c = fdot2(w2[r][15], hc3.h[3], c);
        a2[r] = c;
      }
      #pragma unroll
      for (int r = 0; r < 4; ++r) a2[r] = red8(a2[r]);
      float sel2 = a2[0];
      #pragma unroll
      for (int r = 1; r < 4; ++r) sel2 = (kc == r) ? a2[r] : sel2;

      // ---- tableau combine on kc<4 lanes ----
      if (kc < 4) {
        ksR[e] = b2r + sel2;
        if (e < 5) {
          float acm = 0.f;
          #pragma unroll
          for (int mm = 0; mm <= e; ++mm) acm = __builtin_fmaf(Af[e][mm], ksR[mm], acm);
          z16[traj][orow] = (_Float16)__builtin_fmaf(dt, acm, yR);
        } else {
          float acm = 0.f;
          #pragma unroll
          for (int mm = 0; mm < 6; ++mm) acm = __builtin_fmaf(Bf[mm], ksR[mm], acm);
          yR = __builtin_fmaf(dt, acm, yR);
          z16[traj][orow] = (_Float16)yR;
          out[((long)b * KSTEPS + (i + 1)) * NSTATE + orow] = yR;
        }
      }
      if (e < 5) {
        if (is_u) {
          const double th = CcD[e];
          const float cu0 = (float)(th * th * th - 2.0 * th * th + 1.0);
          const float cu1 = (float)(2.0 * th * th - th * th * th);
          const float cd0 = (float)(th * th * th - 2.0 * th * th + th);
          z16[traj][128 + m] = (_Float16)(cu0 * u0v + cu1 * u1v + cd0 * hd0v);
        }
        if (lt == 5) z16[traj][160] = (_Float16)__builtin_fmaf(Cc[e], dt, tcur);
      } else {
        if (is_u) z16[traj][128 + m] = (_Float16)u1v;   // theta=0 of next step
        if (lt == 5) z16[traj][160] = (_Float16)tn1;
      }
    }

    if (is_u) { uprev = u0v; u0v = u1v; u1v = u2v; }
    dtp  = dt;
    tcur = tn1;
    tn1  = tn2;
  }
}

} // namespace

extern "C" void kernel_launch(void* const* d_in, const int* in_sizes, int n_in,
                              void* d_out, int out_size, void* d_ws, size_t ws_size,
                              hipStream_t stream) {
  const float* ts = (const float*)d_in[0];
  const float* y0 = (const float*)d_in[1];
  const float* us = (const float*)d_in[2];
  const float* W1 = (const float*)d_in[3];
  const float* b1 = (const float*)d_in[4];
  const float* W2 = (const float*)d_in[5];
  const float* b2 = (const float*)d_in[6];
  float* out = (float*)d_out;
  hipLaunchKernelGGL(ode_tsit5_kernel, dim3(32), dim3(512), 0, stream,
                     ts, y0, us, W1, b1, W2, b2, out);
}

// Round 5
// 2448.806 us; speedup vs baseline: 1.5192x; 1.5192x over previous
//
#include <hip/hip_runtime.h>

namespace {

typedef _Float16 h2 __attribute__((ext_vector_type(2)));

constexpr int KSTEPS = 512;
constexpr int NSTATE = 128;
constexpr int NINPUT = 32;
constexpr int HID    = 256;
constexpr int FANIN  = 161;

// z (f16): [y 0..127 | u 128..159 | t 160 | zero pad 161..191]
constexpr int ZST = 192;
// h: 8 chunks, stride 40 f16 (32 valid + 8 pad), conflict-free b128 reads
constexpr int HCH = 40;
constexpr int HST = 8 * HCH;   // 320

__device__ __forceinline__ float fdot2(h2 a, h2 b, float c) {
#if __has_builtin(__builtin_amdgcn_fdot2)
  return __builtin_amdgcn_fdot2(a, b, c, false);
#else
  return c + (float)a[0] * (float)b[0] + (float)a[1] * (float)b[1];
#endif
}

__device__ __forceinline__ float fast_tanh(float x) {
  float e2 = __expf(2.0f * x);
  return 1.0f - 2.0f / (e2 + 1.0f);
}

template <int CTRL>
__device__ __forceinline__ float dpp_add(float x) {
  int y = __builtin_amdgcn_update_dpp(0, __float_as_int(x), CTRL, 0xF, 0xF, false);
  return x + __int_as_float(y);
}
// sum across 8 consecutive lanes (3-step DPP butterfly, VALU pipe only)
__device__ __forceinline__ float red8(float x) {
  x = dpp_add<0xB1>(x);    // xor 1
  x = dpp_add<0x4E>(x);    // xor 2
  x = dpp_add<0x141>(x);   // half-row mirror
  return x;
}

// Barrier with LDS-only drain: skip the vmcnt(0) drain __syncthreads() forces,
// so global out-stores / us-loads stay in flight across stage boundaries.
#define BAR() __asm__ volatile("s_waitcnt lgkmcnt(0)\n\ts_barrier" ::: "memory")

union F4 { float4 f; h2 h[4]; };

// 64 blocks x 256 threads, one trajectory per block (4 waves, 1 wave/SIMD).
// Thread (g=t>>3 in 0..31, kc=t&7):
//   Layer1: hidden rows 8g..8g+7 x z-chunk kc (24 f16).
//   Layer2: state rows 4g..4g+3 x h-chunk kc (32 f16).
// Reductions: 3-step DPP butterfly over the 8 kc lanes. 2 barriers/stage.
__global__ __launch_bounds__(256, 1)
void ode_tsit5_kernel(const float* __restrict__ ts,
                      const float* __restrict__ y0,
                      const float* __restrict__ us,
                      const float* __restrict__ W1,
                      const float* __restrict__ b1,
                      const float* __restrict__ W2,
                      const float* __restrict__ b2,
                      float* __restrict__ out)
{
  const int lt = threadIdx.x;          // 0..255
  const int g  = lt >> 3;              // 0..31
  const int kc = lt & 7;               // 0..7
  const int b  = blockIdx.x;

  __shared__ __align__(16) _Float16 z16[ZST];
  __shared__ __align__(16) _Float16 hs[HST];

  // ---- pack weights into f16-pair registers ----
  // z position p -> W1 column: p<160 -> p+1 (y,u), p==160 -> 0 (t), else 0 (pad).
  h2 w1[8][12];
  #pragma unroll
  for (int r = 0; r < 8; ++r) {
    const float* row = W1 + (long)(8 * g + r) * FANIN;
    #pragma unroll
    for (int i = 0; i < 12; ++i) {
      const int p0 = 24 * kc + 2 * i;
      const int p1 = p0 + 1;
      const float f0 = (p0 < 160) ? row[p0 + 1] : ((p0 == 160) ? row[0] : 0.0f);
      const float f1 = (p1 < 160) ? row[p1 + 1] : ((p1 == 160) ? row[0] : 0.0f);
      w1[r][i] = h2{(_Float16)f0, (_Float16)f1};
    }
  }
  h2 w2[4][16];
  #pragma unroll
  for (int r = 0; r < 4; ++r) {
    const float* row = W2 + (long)(4 * g + r) * HID + 32 * kc;
    #pragma unroll
    for (int i = 0; i < 16; ++i)
      w2[r][i] = h2{(_Float16)row[2 * i], (_Float16)row[2 * i + 1]};
  }

  const int   jrow = 8 * g + kc;                      // layer1 store row for this lane
  const float b1r  = b1[jrow];
  const int   hidx = HCH * (jrow >> 5) + (jrow & 31);
  const int   orow = 4 * g + kc;                      // layer2 row (kc<4)
  const float b2r  = (kc < 4) ? b2[orow] : 0.0f;

  // Tsit5 tableau (b7 = 0 path)
  constexpr float Cc[5] = {0.161f, 0.327f, 0.9f, 0.9800255409045097f, 1.0f};
  constexpr double CcD[5] = {0.161, 0.327, 0.9, 0.9800255409045097, 1.0};
  constexpr float Af[5][5] = {
    {0.161f, 0.f, 0.f, 0.f, 0.f},
    {-0.008480655492356989f, 0.335480655492357f, 0.f, 0.f, 0.f},
    {2.8971530571054935f, -6.359448489975075f, 4.3622954328695815f, 0.f, 0.f},
    {5.325864828439257f, -11.748883564062828f, 7.4955393428898365f, -0.09249506636175525f, 0.f},
    {5.86145544294642f, -12.92096931784711f, 8.159367898576159f, -0.071584973281401f,
     -0.028269050394068383f}};
  constexpr float Bf[6] = {0.09646076681806523f, 0.01f, 0.4798896504144996f,
                           1.379008574103742f, -3.290069515436081f, 2.324710524099774f};

  // ---- init ----
  float yR = 0.0f, ksR[6] = {0.f, 0.f, 0.f, 0.f, 0.f, 0.f};
  if (kc < 4) {
    yR = y0[(long)b * NSTATE + orow];
    z16[orow] = (_Float16)yR;
    out[(long)b * KSTEPS * NSTATE + orow] = yR;
  }
  if (lt < ZST - FANIN) z16[FANIN + lt] = (_Float16)0.0f;  // pad, never rewritten

  const bool is_u = (kc == 4);
  const int  m    = g;                    // u component for kc==4 lanes
  const float* usb = us + (long)b * KSTEPS * NINPUT;
  float u0v = 0.f, u1v = 0.f, u2v = 0.f, uprev = 0.f;
  if (is_u) {
    u0v = usb[m];
    u1v = usb[NINPUT + m];
    z16[128 + m] = (_Float16)u0v;
  }
  float tcur = ts[0], tn1 = ts[1];
  float dtp  = 1.0f;
  if (lt == 5) z16[160] = (_Float16)tcur;

  for (int i = 0; i < KSTEPS - 1; ++i) {
    const float dt = tn1 - tcur;
    const int   i2 = (i + 2 < KSTEPS) ? (i + 2) : (KSTEPS - 1);
    const float tn2 = ts[i2];                       // prefetch for next step
    if (is_u) u2v = usb[(long)i2 * NINPUT + m];     // prefetch for next step

    float hd0v = 0.f;
    if (is_u) hd0v = (i == 0) ? (u1v - u0v) : (u0v - uprev) * (dt / dtp);

    #pragma unroll
    for (int e = 0; e < 6; ++e) {
      BAR();   // z16 ready (LDS-only drain)

      // ---- layer 1: 8 rows x 24-f16 z chunk, 2 chains per row for ILP ----
      const F4* zp = (const F4*)(&z16[24 * kc]);
      F4 zc0 = zp[0], zc1 = zp[1], zc2 = zp[2];
      float acc[8];
      #pragma unroll
      for (int r = 0; r < 8; ++r) {
        float a0 = fdot2(w1[r][0], zc0.h[0], 0.0f);
        float a1 = fdot2(w1[r][1], zc0.h[1], 0.0f);
        a0 = fdot2(w1[r][2],  zc0.h[2], a0);
        a1 = fdot2(w1[r][3],  zc0.h[3], a1);
        a0 = fdot2(w1[r][4],  zc1.h[0], a0);
        a1 = fdot2(w1[r][5],  zc1.h[1], a1);
        a0 = fdot2(w1[r][6],  zc1.h[2], a0);
        a1 = fdot2(w1[r][7],  zc1.h[3], a1);
        a0 = fdot2(w1[r][8],  zc2.h[0], a0);
        a1 = fdot2(w1[r][9],  zc2.h[1], a1);
        a0 = fdot2(w1[r][10], zc2.h[2], a0);
        a1 = fdot2(w1[r][11], zc2.h[3], a1);
        acc[r] = a0 + a1;
      }
      #pragma unroll
      for (int r = 0; r < 8; ++r) acc[r] = red8(acc[r]);
      // lane kc stores row 8g+kc
      float sel = acc[0];
      #pragma unroll
      for (int r = 1; r < 8; ++r) sel = (kc == r) ? acc[r] : sel;
      hs[hidx] = (_Float16)fast_tanh(b1r + sel);

      BAR();   // hs ready

      // ---- layer 2: 4 rows x 32-f16 h chunk, 2 chains per row ----
      const F4* hp4 = (const F4*)(&hs[HCH * kc]);
      F4 hc0 = hp4[0], hc1 = hp4[1], hc2 = hp4[2], hc3 = hp4[3];
      float a2[4];
      #pragma unroll
      for (int r = 0; r < 4; ++r) {
        float c0 = fdot2(w2[r][0], hc0.h[0], 0.0f);
        float c1 = fdot2(w2[r][1], hc0.h[1], 0.0f);
        c0 = fdot2(w2[r][2],  hc0.h[2], c0);
        c1 = fdot2(w2[r][3],  hc0.h[3], c1);
        c0 = fdot2(w2[r][4],  hc1.h[0], c0);
        c1 = fdot2(w2[r][5],  hc1.h[1], c1);
        c0 = fdot2(w2[r][6],  hc1.h[2], c0);
        c1 = fdot2(w2[r][7],  hc1.h[3], c1);
        c0 = fdot2(w2[r][8],  hc2.h[0], c0);
        c1 = fdot2(w2[r][9],  hc2.h[1], c1);
        c0 = fdot2(w2[r][10], hc2.h[2], c0);
        c1 = fdot2(w2[r][11], hc2.h[3], c1);
        c0 = fdot2(w2[r][12], hc3.h[0], c0);
        c1 = fdot2(w2[r][13], hc3.h[1], c1);
        c0 = fdot2(w2[r][14], hc3.h[2], c0);
        c1 = fdot2(w2[r][15], hc3.h[3], c1);
        a2[r] = c0 + c1;
      }
      #pragma unroll
      for (int r = 0; r < 4; ++r) a2[r] = red8(a2[r]);
      float sel2 = a2[0];
      #pragma unroll
      for (int r = 1; r < 4; ++r) sel2 = (kc == r) ? a2[r] : sel2;

      // ---- tableau combine on kc<4 lanes ----
      if (kc < 4) {
        ksR[e] = b2r + sel2;
        if (e < 5) {
          float acm = 0.f;
          #pragma unroll
          for (int mm = 0; mm <= e; ++mm) acm = __builtin_fmaf(Af[e][mm], ksR[mm], acm);
          z16[orow] = (_Float16)__builtin_fmaf(dt, acm, yR);
        } else {
          float acm = 0.f;
          #pragma unroll
          for (int mm = 0; mm < 6; ++mm) acm = __builtin_fmaf(Bf[mm], ksR[mm], acm);
          yR = __builtin_fmaf(dt, acm, yR);
          z16[orow] = (_Float16)yR;
          out[((long)b * KSTEPS + (i + 1)) * NSTATE + orow] = yR;
        }
      }
      if (e < 5) {
        if (is_u) {
          const double th = CcD[e];
          const float cu0 = (float)(th * th * th - 2.0 * th * th + 1.0);
          const float cu1 = (float)(2.0 * th * th - th * th * th);
          const float cd0 = (float)(th * th * th - 2.0 * th * th + th);
          z16[128 + m] = (_Float16)(cu0 * u0v + cu1 * u1v + cd0 * hd0v);
        }
        if (lt == 5) z16[160] = (_Float16)__builtin_fmaf(Cc[e], dt, tcur);
      } else {
        if (is_u) z16[128 + m] = (_Float16)u1v;   // theta=0 of next step
        if (lt == 5) z16[160] = (_Float16)tn1;
      }
    }

    if (is_u) { uprev = u0v; u0v = u1v; u1v = u2v; }
    dtp  = dt;
    tcur = tn1;
    tn1  = tn2;
  }
}

} // namespace

extern "C" void kernel_launch(void* const* d_in, const int* in_sizes, int n_in,
                              void* d_out, int out_size, void* d_ws, size_t ws_size,
                              hipStream_t stream) {
  const float* ts = (const float*)d_in[0];
  const float* y0 = (const float*)d_in[1];
  const float* us = (const float*)d_in[2];
  const float* W1 = (const float*)d_in[3];
  const float* b1 = (const float*)d_in[4];
  const float* W2 = (const float*)d_in[5];
  const float* b2 = (const float*)d_in[6];
  float* out = (float*)d_out;
  hipLaunchKernelGGL(ode_tsit5_kernel, dim3(64), dim3(256), 0, stream,
                     ts, y0, us, W1, b1, W2, b2, out);
}